// Round 1
// baseline (14024.811 us; speedup 1.0000x reference)
//
#include <hip/hip_runtime.h>
#include <math.h>

// Problem constants (from reference)
#define NROWS 131072
#define DIN   16
#define DC    16
#define UNITS 512
#define BINS  10
#define DT    8
#define FIN   24     // DT + DIMS_C
#define FOUT  248    // DT * (3*BINS + 1)
#define TM    16     // rows per workgroup

// One coupling block: z[:,trans] <- RQS(z[:,trans]; MLP([z[:,cond], c]))
// logdet[row] += sum_d lj
// Mask math: block b has p = b>>1, inv = b&1; m[b][j] = ((j>>p)&1) ^ inv.
// cond dims = {j : m=1} (bit p == 1^inv), trans dims = {j : m=0} (bit p == inv).
// i-th (sorted) member with bit p == v:  ((i>>p)<<(p+1)) | (v<<p) | (i & ((1<<p)-1))
__global__ __launch_bounds__(256, 2)
void flow_block_kernel(const float* __restrict__ z,
                       const float* __restrict__ c,
                       const float* __restrict__ W0, const float* __restrict__ b0,
                       const float* __restrict__ W1, const float* __restrict__ b1,
                       const float* __restrict__ W2, const float* __restrict__ b2,
                       float* __restrict__ zout, float* __restrict__ logdet,
                       int p, int inv)
{
    __shared__ float lds[2 * TM * UNITS];   // 64 KB: H0 tile + H1 tile
    float* H0 = lds;
    float* H1 = lds + TM * UNITS;

    const int t = threadIdx.x;
    const int row0 = blockIdx.x * TM;
    const int lowmask = (1 << p) - 1;
    const int cv = 1 - inv;   // cond-dim bit value
    const int tv = inv;       // trans-dim bit value

    float acc0[TM], acc1[TM];

    // ---------- GEMM1: H0 = relu([z_cond, c] @ W0 + b0), cols (t, t+256) ----------
    {
        const float ba = b0[t], bb = b0[t + 256];
        #pragma unroll
        for (int r = 0; r < TM; ++r) { acc0[r] = ba; acc1[r] = bb; }
        #pragma unroll
        for (int k = 0; k < FIN; ++k) {
            const float wa = W0[k * UNITS + t];
            const float wb = W0[k * UNITS + t + 256];
            int col = 0;
            if (k < 8) col = ((k >> p) << (p + 1)) | (cv << p) | (k & lowmask);
            #pragma unroll
            for (int r = 0; r < TM; ++r) {
                const int row = row0 + r;
                const float a = (k < 8) ? z[row * DIN + col]
                                        : c[row * DC + (k - 8)];
                acc0[r] = fmaf(a, wa, acc0[r]);
                acc1[r] = fmaf(a, wb, acc1[r]);
            }
        }
        #pragma unroll
        for (int r = 0; r < TM; ++r) {
            H0[r * UNITS + t]       = fmaxf(acc0[r], 0.f);
            H0[r * UNITS + t + 256] = fmaxf(acc1[r], 0.f);
        }
    }
    __syncthreads();

    // ---------- GEMM2: H1 = relu(H0 @ W1 + b1), cols (t, t+256) ----------
    {
        const float ba = b1[t], bb = b1[t + 256];
        #pragma unroll
        for (int r = 0; r < TM; ++r) { acc0[r] = ba; acc1[r] = bb; }
        for (int k = 0; k < UNITS; k += 4) {
            const float wa0 = W1[(k + 0) * UNITS + t];
            const float wa1 = W1[(k + 1) * UNITS + t];
            const float wa2 = W1[(k + 2) * UNITS + t];
            const float wa3 = W1[(k + 3) * UNITS + t];
            const float wb0 = W1[(k + 0) * UNITS + t + 256];
            const float wb1 = W1[(k + 1) * UNITS + t + 256];
            const float wb2 = W1[(k + 2) * UNITS + t + 256];
            const float wb3 = W1[(k + 3) * UNITS + t + 256];
            #pragma unroll
            for (int r = 0; r < TM; ++r) {
                const float4 h = *(const float4*)(&H0[r * UNITS + k]);
                acc0[r] = fmaf(h.x, wa0, acc0[r]);
                acc0[r] = fmaf(h.y, wa1, acc0[r]);
                acc0[r] = fmaf(h.z, wa2, acc0[r]);
                acc0[r] = fmaf(h.w, wa3, acc0[r]);
                acc1[r] = fmaf(h.x, wb0, acc1[r]);
                acc1[r] = fmaf(h.y, wb1, acc1[r]);
                acc1[r] = fmaf(h.z, wb2, acc1[r]);
                acc1[r] = fmaf(h.w, wb3, acc1[r]);
            }
        }
        #pragma unroll
        for (int r = 0; r < TM; ++r) {
            H1[r * UNITS + t]       = fmaxf(acc0[r], 0.f);
            H1[r * UNITS + t + 256] = fmaxf(acc1[r], 0.f);
        }
    }
    __syncthreads();

    // ---------- GEMM3: params = H1 @ W2 + b2, col t (t < 248) ----------
    float accp[TM];
    if (t < FOUT) {
        const float bp = b2[t];
        #pragma unroll
        for (int r = 0; r < TM; ++r) accp[r] = bp;
        for (int k = 0; k < UNITS; k += 4) {
            const float w0  = W2[(k + 0) * FOUT + t];
            const float w1  = W2[(k + 1) * FOUT + t];
            const float w2v = W2[(k + 2) * FOUT + t];
            const float w3  = W2[(k + 3) * FOUT + t];
            #pragma unroll
            for (int r = 0; r < TM; ++r) {
                const float4 h = *(const float4*)(&H1[r * UNITS + k]);
                accp[r] = fmaf(h.x, w0,  accp[r]);
                accp[r] = fmaf(h.y, w1,  accp[r]);
                accp[r] = fmaf(h.z, w2v, accp[r]);
                accp[r] = fmaf(h.w, w3,  accp[r]);
            }
        }
    }
    __syncthreads();               // all H0 reads finished long ago; reuse as params
    float* P = H0;                 // params tile [TM][FOUT]
    if (t < FOUT) {
        #pragma unroll
        for (int r = 0; r < TM; ++r) P[r * FOUT + t] = accp[r];
    }
    __syncthreads();

    // ---------- RQS spline: threads 0..127 handle (row r, trans-dim d) ----------
    float ljv = 0.f;
    if (t < TM * DT) {
        const int r = t >> 3;
        const int d = t & 7;
        const int row = row0 + r;
        const int td = ((d >> p) << (p + 1)) | (tv << p) | (d & lowmask);
        const float* pp = &P[r * FOUT + d * 31];

        // widths: 0.001 + 0.99 * softmax(uw)
        float mw = pp[0];
        #pragma unroll
        for (int i = 1; i < BINS; ++i) mw = fmaxf(mw, pp[i]);
        float w[BINS]; float sw = 0.f;
        #pragma unroll
        for (int i = 0; i < BINS; ++i) { w[i] = expf(pp[i] - mw); sw += w[i]; }
        const float rw = (1.0f - 0.001f * BINS) / sw;
        #pragma unroll
        for (int i = 0; i < BINS; ++i) w[i] = 0.001f + rw * w[i];

        // heights: 0.001 + 0.99 * softmax(uh)
        float mh = pp[BINS];
        #pragma unroll
        for (int i = 1; i < BINS; ++i) mh = fmaxf(mh, pp[BINS + i]);
        float hh[BINS]; float sh = 0.f;
        #pragma unroll
        for (int i = 0; i < BINS; ++i) { hh[i] = expf(pp[BINS + i] - mh); sh += hh[i]; }
        const float rh = (1.0f - 0.001f * BINS) / sh;
        #pragma unroll
        for (int i = 0; i < BINS; ++i) hh[i] = 0.001f + rh * hh[i];

        // derivatives: 0.001 + softplus(ud)  (stable form, matches jax)
        float dd[BINS + 1];
        #pragma unroll
        for (int i = 0; i < BINS + 1; ++i) {
            const float u = pp[2 * BINS + i];
            dd[i] = 0.001f + fmaxf(u, 0.f) + log1pf(expf(-fabsf(u)));
        }

        // knot cumsums
        float cw[BINS + 1], ch[BINS + 1];
        cw[0] = 0.f; ch[0] = 0.f;
        #pragma unroll
        for (int i = 0; i < BINS; ++i) { cw[i + 1] = cw[i] + w[i]; ch[i + 1] = ch[i] + hh[i]; }

        const float x = z[row * DIN + td];

        // idx = clip(sum(x >= cw) - 1, 0, BINS-1)
        int cnt = 0;
        #pragma unroll
        for (int i = 0; i <= BINS; ++i) cnt += (x >= cw[i]) ? 1 : 0;
        int idx = cnt - 1;
        idx = idx < 0 ? 0 : (idx > BINS - 1 ? BINS - 1 : idx);

        float xk = 0.f, wk = 1.f, yk = 0.f, hk = 1.f, dk = 1.f, dk1 = 1.f;
        #pragma unroll
        for (int i = 0; i < BINS; ++i) {
            if (idx == i) { xk = cw[i]; wk = w[i]; yk = ch[i]; hk = hh[i]; dk = dd[i]; dk1 = dd[i + 1]; }
        }

        float th = (x - xk) / wk;
        th = fminf(fmaxf(th, 0.f), 1.f);
        const float s   = hk / wk;
        const float t1  = th * (1.f - th);
        const float den = s + (dk1 + dk - 2.f * s) * t1;
        const float num = s * th * th + dk * t1;
        const float y   = yk + hk * num / den;
        const float om  = 1.f - th;
        ljv = 2.f * logf(s)
            + logf(dk1 * th * th + 2.f * s * t1 + dk * om * om)
            - 2.f * logf(den);

        zout[row * DIN + td] = y;
    }

    // reduce 8 trans-dims per row (lanes grouped by 8 within the wave)
    float v = ljv;
    v += __shfl_down(v, 4, 8);
    v += __shfl_down(v, 2, 8);
    v += __shfl_down(v, 1, 8);
    if (t < TM * DT && (t & 7) == 0) {
        logdet[row0 + (t >> 3)] += v;   // exclusive owner; blocks are sequential kernels
    }
}

extern "C" void kernel_launch(void* const* d_in, const int* in_sizes, int n_in,
                              void* d_out, int out_size, void* d_ws, size_t ws_size,
                              hipStream_t stream) {
    (void)in_sizes; (void)n_in; (void)out_size; (void)ws_size;
    const float* x  = (const float*)d_in[0];
    const float* c  = (const float*)d_in[1];
    const float* W0 = (const float*)d_in[2];
    const float* b0 = (const float*)d_in[3];
    const float* W1 = (const float*)d_in[4];
    const float* b1 = (const float*)d_in[5];
    const float* W2 = (const float*)d_in[6];
    const float* b2 = (const float*)d_in[7];
    float* out = (float*)d_out;
    float* z   = (float*)d_ws;     // [NROWS, DIN] running state

    hipMemcpyAsync(z, x, (size_t)NROWS * DIN * sizeof(float),
                   hipMemcpyDeviceToDevice, stream);
    hipMemsetAsync(out, 0, (size_t)NROWS * sizeof(float), stream);

    dim3 grid(NROWS / TM), block(256);
    for (int b = 0; b < 8; ++b) {
        const int p = b >> 1, inv = b & 1;
        flow_block_kernel<<<grid, block, 0, stream>>>(
            z, c,
            W0 + (size_t)b * FIN * UNITS,   b0 + (size_t)b * UNITS,
            W1 + (size_t)b * UNITS * UNITS, b1 + (size_t)b * UNITS,
            W2 + (size_t)b * UNITS * FOUT,  b2 + (size_t)b * FOUT,
            z, out, p, inv);
    }
}

// Round 3
// 3130.794 us; speedup vs baseline: 4.4796x; 4.4796x over previous
//
#include <hip/hip_runtime.h>
#include <math.h>

#define NROWS 131072
#define DIN   16
#define DC    16
#define UNITS 512
#define BINS  10
#define DT    8
#define FOUT  248
#define M_TILE 64               // rows per workgroup
#define NWG   (NROWS / M_TILE)  // 2048

// d_ws byte offsets
#define Z_OFF    0u
#define W0T_OFF  8388608u   // [8][512][32]  fp16
#define W1T_OFF  8650752u   // [8][512][512] fp16
#define W2T_OFF  12845056u  // [8][256][512] fp16 (m>=248 zeroed)

typedef _Float16 h16x8 __attribute__((ext_vector_type(8)));
typedef float    f32x4 __attribute__((ext_vector_type(4)));

union Frag { h16x8 v; uint4 q; unsigned int u32[4]; _Float16 h[8]; };

static __device__ inline unsigned int pack2h(float lo, float hi) {
    union { _Float16 h[2]; unsigned int u; } x;
    x.h[0] = (_Float16)lo; x.h[1] = (_Float16)hi;
    return x.u;
}

// ---------------- weight transpose/convert prologue ----------------
__global__ __launch_bounds__(256)
void prep_weights(const float* __restrict__ W0, const float* __restrict__ W1,
                  const float* __restrict__ W2, _Float16* __restrict__ W0T,
                  _Float16* __restrict__ W1T, _Float16* __restrict__ W2T)
{
    const int idx = blockIdx.x * 256 + threadIdx.x;
    const int SZ0 = 8 * 512 * 32;       // 131072
    const int SZ1 = 8 * 512 * 512;      // 2097152
    const int SZ2 = 8 * 256 * 512;      // 1048576
    if (idx < SZ0) {
        int b = idx >> 14, r = idx & 16383, m = r >> 5, k = r & 31;
        W0T[idx] = (k < 24) ? (_Float16)W0[b * 12288 + k * 512 + m] : (_Float16)0.f;
    } else if (idx < SZ0 + SZ1) {
        int i = idx - SZ0;
        int b = i >> 18, r = i & 262143, m = r >> 9, k = r & 511;
        W1T[i] = (_Float16)W1[(b << 18) + (k << 9) + m];
    } else if (idx < SZ0 + SZ1 + SZ2) {
        int i = idx - SZ0 - SZ1;
        int b = i >> 17, r = i & 131071, m = r >> 9, k = r & 511;
        W2T[i] = (m < FOUT) ? (_Float16)W2[b * (512 * FOUT) + k * FOUT + m] : (_Float16)0.f;
    }
}

// ---------------- fused coupling block ----------------
__global__ __launch_bounds__(512, 2)
void flow_block_kernel(const float* __restrict__ z, const float* __restrict__ c,
                       const _Float16* __restrict__ W0T, const float* __restrict__ b0,
                       const _Float16* __restrict__ W1T, const float* __restrict__ b1,
                       const _Float16* __restrict__ W2T, const float* __restrict__ b2,
                       float* __restrict__ zout, float* __restrict__ logdet,
                       int p, int inv)
{
    __shared__ __align__(16) char smem[65536];

    const int t    = threadIdx.x;
    const int wave = t >> 6;
    const int lane = t & 63;
    const int quad = lane >> 4;
    const int l15  = lane & 15;
    const int row0 = blockIdx.x * M_TILE;
    const int lowmask = (1 << p) - 1;
    const int cv = 1 - inv, tv = inv;
    const int rtb = wave >> 2;          // base row-tile: waves 0-3 -> {0,2}, 4-7 -> {1,3}
    const int utm = wave & 3;           // unit-tile residue

    // ---- GEMM1 B-frags: X^T = [z_cond | c | 0pad], per row-tile ----
    Frag bx[2];
    #pragma unroll
    for (int i = 0; i < 2; ++i) {
        const int n = (rtb + 2 * i) * 16 + l15;
        const float* zr = z + (size_t)(row0 + n) * DIN;
        const float* cr = c + (size_t)(row0 + n) * DC;
        float v[8];
        if (quad == 0) {
            #pragma unroll
            for (int j = 0; j < 8; ++j) {
                const int col = ((j >> p) << (p + 1)) | (cv << p) | (j & lowmask);
                v[j] = zr[col];
            }
        } else if (quad == 1) {
            #pragma unroll
            for (int j = 0; j < 8; ++j) v[j] = cr[j];
        } else if (quad == 2) {
            #pragma unroll
            for (int j = 0; j < 8; ++j) v[j] = cr[8 + j];
        } else {
            #pragma unroll
            for (int j = 0; j < 8; ++j) v[j] = 0.f;
        }
        #pragma unroll
        for (int j = 0; j < 4; ++j) bx[i].u32[j] = pack2h(v[2 * j], v[2 * j + 1]);
    }

    // ---- GEMM1: H0^T = relu(W0T @ X^T + b0), straight into swizzled LDS ----
    #pragma unroll
    for (int j = 0; j < 8; ++j) {
        const int ut = utm + 4 * j;
        Frag a; a.q = *(const uint4*)(W0T + (ut * 16 + l15) * 32 + quad * 8);
        const f32x4 bias = *(const f32x4*)(b0 + ut * 16 + quad * 4);
        const int m0 = ut * 16 + quad * 4;
        #pragma unroll
        for (int i = 0; i < 2; ++i) {
            f32x4 acc = __builtin_amdgcn_mfma_f32_16x16x32_f16(a.v, bx[i].v, bias, 0, 0, 0);
            const int n = (rtb + 2 * i) * 16 + l15;
            uint2 w2;
            w2.x = pack2h(fmaxf(acc.x, 0.f), fmaxf(acc.y, 0.f));
            w2.y = pack2h(fmaxf(acc.z, 0.f), fmaxf(acc.w, 0.f));
            const int addr = n * 1024 + (((m0 >> 3) ^ (n & 7)) * 16) + ((m0 & 4) * 2);
            *(uint2*)(smem + addr) = w2;
        }
    }
    __syncthreads();

    // ---- GEMM2: H1 = relu(H0 @ W1 + b1), H1 kept in registers ----
    f32x4 h1[8][2];
    #pragma unroll
    for (int j = 0; j < 8; ++j) {
        const int ut = utm + 4 * j;
        const f32x4 bias = *(const f32x4*)(b1 + ut * 16 + quad * 4);
        h1[j][0] = bias; h1[j][1] = bias;
    }
    #pragma unroll 2
    for (int ks = 0; ks < 16; ++ks) {
        Frag B0, B1;
        {
            const int n0 = rtb * 16 + l15;
            const int n1 = (rtb + 2) * 16 + l15;
            B0.v = *(const h16x8*)(smem + n0 * 1024 + (((ks * 4 + quad) ^ (n0 & 7)) * 16));
            B1.v = *(const h16x8*)(smem + n1 * 1024 + (((ks * 4 + quad) ^ (n1 & 7)) * 16));
        }
        #pragma unroll
        for (int j = 0; j < 8; ++j) {
            const int ut = utm + 4 * j;
            Frag a; a.q = *(const uint4*)(W1T + (ut * 16 + l15) * 512 + ks * 32 + quad * 8);
            h1[j][0] = __builtin_amdgcn_mfma_f32_16x16x32_f16(a.v, B0.v, h1[j][0], 0, 0, 0);
            h1[j][1] = __builtin_amdgcn_mfma_f32_16x16x32_f16(a.v, B1.v, h1[j][1], 0, 0, 0);
        }
    }
    __syncthreads();

    // ---- GEMM3: P = H1 @ W2 + b2, H1 staged through LDS in 128-unit chunks ----
    f32x4 pacc[2][4];
    #pragma unroll
    for (int i2 = 0; i2 < 2; ++i2) {
        const int m0 = (wave * 2 + i2) * 16 + quad * 4;
        f32x4 bias;
        if (m0 < FOUT) bias = *(const f32x4*)(b2 + m0);
        else { bias.x = 0.f; bias.y = 0.f; bias.z = 0.f; bias.w = 0.f; }
        #pragma unroll
        for (int rt = 0; rt < 4; ++rt) pacc[i2][rt] = bias;
    }
    for (int c2 = 0; c2 < 4; ++c2) {
        // stage H1 units [c2*128, c2*128+128) -> LDS (16 KB, swizzled)
        #pragma unroll
        for (int jj = 0; jj < 2; ++jj) {
            const int j  = 2 * c2 + jj;
            const int ut = utm + 4 * j;                 // in [8*c2, 8*c2+8)
            const int m0l = (ut - c2 * 8) * 16 + quad * 4;  // 0..127
            #pragma unroll
            for (int i = 0; i < 2; ++i) {
                const int n = (rtb + 2 * i) * 16 + l15;
                uint2 w2;
                w2.x = pack2h(fmaxf(h1[j][i].x, 0.f), fmaxf(h1[j][i].y, 0.f));
                w2.y = pack2h(fmaxf(h1[j][i].z, 0.f), fmaxf(h1[j][i].w, 0.f));
                const int addr = n * 256 + ((((m0l >> 3) ^ (n & 7)) & 15) * 16) + ((m0l & 4) * 2);
                *(uint2*)(smem + addr) = w2;
            }
        }
        __syncthreads();
        #pragma unroll
        for (int ks2 = 0; ks2 < 4; ++ks2) {
            Frag B[4];
            #pragma unroll
            for (int rt = 0; rt < 4; ++rt) {
                const int n = rt * 16 + l15;
                const int ch = ((ks2 * 4 + quad) ^ (n & 7)) & 15;
                B[rt].v = *(const h16x8*)(smem + n * 256 + ch * 16);
            }
            #pragma unroll
            for (int i2 = 0; i2 < 2; ++i2) {
                const int ut2 = wave * 2 + i2;
                Frag a; a.q = *(const uint4*)(W2T + (ut2 * 16 + l15) * 512 + c2 * 128 + ks2 * 32 + quad * 8);
                #pragma unroll
                for (int rt = 0; rt < 4; ++rt)
                    pacc[i2][rt] = __builtin_amdgcn_mfma_f32_16x16x32_f16(a.v, B[rt].v, pacc[i2][rt], 0, 0, 0);
            }
        }
        __syncthreads();
    }

    // ---- dump P (fp32) to LDS for the spline phase: [64 rows][252] ----
    #pragma unroll
    for (int i2 = 0; i2 < 2; ++i2) {
        const int m0 = (wave * 2 + i2) * 16 + quad * 4;
        if (m0 < FOUT) {
            #pragma unroll
            for (int rt = 0; rt < 4; ++rt) {
                const int n = rt * 16 + l15;
                *(f32x4*)(smem + n * 1008 + m0 * 4) = pacc[i2][rt];
            }
        }
    }
    __syncthreads();

    // ---- RQS spline: thread t -> (row r = t>>3, dim d = t&7) ----
    {
        const int r = t >> 3;
        const int d = t & 7;
        const int row = row0 + r;
        const int td = ((d >> p) << (p + 1)) | (tv << p) | (d & lowmask);
        const float* pp = (const float*)(smem + r * 1008) + d * 31;

        float mw = pp[0];
        #pragma unroll
        for (int i = 1; i < BINS; ++i) mw = fmaxf(mw, pp[i]);
        float w[BINS]; float sw = 0.f;
        #pragma unroll
        for (int i = 0; i < BINS; ++i) { w[i] = expf(pp[i] - mw); sw += w[i]; }
        const float rw = (1.0f - 0.001f * BINS) / sw;
        #pragma unroll
        for (int i = 0; i < BINS; ++i) w[i] = 0.001f + rw * w[i];

        float mh = pp[BINS];
        #pragma unroll
        for (int i = 1; i < BINS; ++i) mh = fmaxf(mh, pp[BINS + i]);
        float hh[BINS]; float sh = 0.f;
        #pragma unroll
        for (int i = 0; i < BINS; ++i) { hh[i] = expf(pp[BINS + i] - mh); sh += hh[i]; }
        const float rh = (1.0f - 0.001f * BINS) / sh;
        #pragma unroll
        for (int i = 0; i < BINS; ++i) hh[i] = 0.001f + rh * hh[i];

        float dd[BINS + 1];
        #pragma unroll
        for (int i = 0; i < BINS + 1; ++i) {
            const float u = pp[2 * BINS + i];
            dd[i] = 0.001f + fmaxf(u, 0.f) + log1pf(expf(-fabsf(u)));
        }

        float cw[BINS + 1], ch[BINS + 1];
        cw[0] = 0.f; ch[0] = 0.f;
        #pragma unroll
        for (int i = 0; i < BINS; ++i) { cw[i + 1] = cw[i] + w[i]; ch[i + 1] = ch[i] + hh[i]; }

        const float x = z[(size_t)row * DIN + td];

        int cnt = 0;
        #pragma unroll
        for (int i = 0; i <= BINS; ++i) cnt += (x >= cw[i]) ? 1 : 0;
        int idx = cnt - 1;
        idx = idx < 0 ? 0 : (idx > BINS - 1 ? BINS - 1 : idx);

        float xk = 0.f, wk = 1.f, yk = 0.f, hk = 1.f, dk = 1.f, dk1 = 1.f;
        #pragma unroll
        for (int i = 0; i < BINS; ++i) {
            if (idx == i) { xk = cw[i]; wk = w[i]; yk = ch[i]; hk = hh[i]; dk = dd[i]; dk1 = dd[i + 1]; }
        }

        float th = (x - xk) / wk;
        th = fminf(fmaxf(th, 0.f), 1.f);
        const float s   = hk / wk;
        const float t1  = th * (1.f - th);
        const float den = s + (dk1 + dk - 2.f * s) * t1;
        const float num = s * th * th + dk * t1;
        const float y   = yk + hk * num / den;
        const float om  = 1.f - th;
        float ljv = 2.f * logf(s)
                  + logf(dk1 * th * th + 2.f * s * t1 + dk * om * om)
                  - 2.f * logf(den);

        zout[(size_t)row * DIN + td] = y;

        float v = ljv;
        v += __shfl_down(v, 4, 8);
        v += __shfl_down(v, 2, 8);
        v += __shfl_down(v, 1, 8);
        if ((t & 7) == 0) logdet[row0 + (t >> 3)] += v;
    }
}

extern "C" void kernel_launch(void* const* d_in, const int* in_sizes, int n_in,
                              void* d_out, int out_size, void* d_ws, size_t ws_size,
                              hipStream_t stream) {
    (void)in_sizes; (void)n_in; (void)out_size; (void)ws_size;
    const float* x  = (const float*)d_in[0];
    const float* c  = (const float*)d_in[1];
    const float* W0 = (const float*)d_in[2];
    const float* b0 = (const float*)d_in[3];
    const float* W1 = (const float*)d_in[4];
    const float* b1 = (const float*)d_in[5];
    const float* W2 = (const float*)d_in[6];
    const float* b2 = (const float*)d_in[7];
    float* out = (float*)d_out;

    char* ws = (char*)d_ws;
    float* z = (float*)(ws + Z_OFF);
    _Float16* W0T = (_Float16*)(ws + W0T_OFF);
    _Float16* W1T = (_Float16*)(ws + W1T_OFF);
    _Float16* W2T = (_Float16*)(ws + W2T_OFF);

    hipMemcpyAsync(z, x, (size_t)NROWS * DIN * sizeof(float),
                   hipMemcpyDeviceToDevice, stream);
    hipMemsetAsync(out, 0, (size_t)NROWS * sizeof(float), stream);

    prep_weights<<<12800, 256, 0, stream>>>(W0, W1, W2, W0T, W1T, W2T);

    dim3 grid(NWG), block(512);
    for (int b = 0; b < 8; ++b) {
        const int p = b >> 1, inv = b & 1;
        flow_block_kernel<<<grid, block, 0, stream>>>(
            z, c,
            W0T + (size_t)b * 512 * 32, b0 + (size_t)b * UNITS,
            W1T + (size_t)b * 512 * 512, b1 + (size_t)b * UNITS,
            W2T + (size_t)b * 256 * 512, b2 + (size_t)b * FOUT,
            z, out, p, inv);
    }
}

// Round 4
// 2071.871 us; speedup vs baseline: 6.7692x; 1.5111x over previous
//
#include <hip/hip_runtime.h>
#include <math.h>

#define NROWS 131072
#define DIN   16
#define DC    16
#define UNITS 512
#define BINS  10
#define DT    8
#define FOUT  248
#define M_TILE 64               // rows per workgroup
#define NWG   (NROWS / M_TILE)  // 2048

// d_ws byte offsets
#define Z_OFF    0u
#define W0F_OFF  8388608u   // [8][32 ut][512]          fp16, fragment-major
#define W1F_OFF  8650752u   // [8][32 ut][16 ks][512]   fp16, fragment-major
#define W2F_OFF  12845056u  // [8][16 ut2][4 c2][4 ks2][512] fp16, fragment-major
 
typedef _Float16 h16x8 __attribute__((ext_vector_type(8)));
typedef float    f32x4 __attribute__((ext_vector_type(4)));

union Frag { h16x8 v; uint4 q; unsigned int u32[4]; _Float16 h[8]; };

static __device__ inline unsigned int pack2h(float lo, float hi) {
    union { _Float16 h[2]; unsigned int u; } x;
    x.h[0] = (_Float16)lo; x.h[1] = (_Float16)hi;
    return x.u;
}

// ---------------- weight convert prologue: fragment-major layouts ----------------
// lane = quad*16 + l15.  A-frag element j of lane -> weight (m, k):
//   m = ut*16 + l15,  k = kbase + quad*8 + j
__global__ __launch_bounds__(256)
void prep_weights(const float* __restrict__ W0, const float* __restrict__ W1,
                  const float* __restrict__ W2, _Float16* __restrict__ W0F,
                  _Float16* __restrict__ W1F, _Float16* __restrict__ W2F)
{
    const int idx = blockIdx.x * 256 + threadIdx.x;
    const int SZ0 = 8 * 32 * 512;           // 131072
    const int SZ1 = 8 * 32 * 16 * 512;      // 2097152
    const int SZ2 = 8 * 16 * 4 * 4 * 512;   // 1048576
    if (idx < SZ0) {
        int b = idx >> 14, r = idx & 16383;
        int ut = r >> 9, le = r & 511;
        int lane = le >> 3, j = le & 7;
        int quad = lane >> 4, l15 = lane & 15;
        int m = ut * 16 + l15, k = quad * 8 + j;
        W0F[idx] = (k < 24) ? (_Float16)W0[b * (24 * 512) + k * 512 + m] : (_Float16)0.f;
    } else if (idx < SZ0 + SZ1) {
        int i = idx - SZ0;
        int b = i >> 18, r = i & 262143;
        int ut = r >> 13, r2 = r & 8191;
        int ks = r2 >> 9, le = r2 & 511;
        int lane = le >> 3, j = le & 7;
        int quad = lane >> 4, l15 = lane & 15;
        int m = ut * 16 + l15, k = ks * 32 + quad * 8 + j;
        W1F[i] = (_Float16)W1[(b << 18) + k * 512 + m];
    } else if (idx < SZ0 + SZ1 + SZ2) {
        int i = idx - SZ0 - SZ1;
        int b = i >> 17, r = i & 131071;
        int ut2 = r >> 13, r2 = r & 8191;
        int c2 = r2 >> 11, r3 = r2 & 2047;
        int ks2 = r3 >> 9, le = r3 & 511;
        int lane = le >> 3, j = le & 7;
        int quad = lane >> 4, l15 = lane & 15;
        int m = ut2 * 16 + l15, k = c2 * 128 + ks2 * 32 + quad * 8 + j;
        W2F[i] = (m < FOUT) ? (_Float16)W2[b * (512 * FOUT) + k * FOUT + m] : (_Float16)0.f;
    }
}

// ---------------- fused coupling block ----------------
__global__ __launch_bounds__(512, 2)
void flow_block_kernel(const float* __restrict__ z, const float* __restrict__ c,
                       const _Float16* __restrict__ W0F, const float* __restrict__ b0,
                       const _Float16* __restrict__ W1F, const float* __restrict__ b1,
                       const _Float16* __restrict__ W2F, const float* __restrict__ b2,
                       float* __restrict__ zout, float* __restrict__ logdet,
                       int p, int inv)
{
    __shared__ __align__(16) char smem[65536];

    const int t    = threadIdx.x;
    const int wave = t >> 6;
    const int lane = t & 63;
    const int quad = lane >> 4;
    const int l15  = lane & 15;
    const int row0 = blockIdx.x * M_TILE;
    const int lowmask = (1 << p) - 1;
    const int cv = 1 - inv, tv = inv;
    const int rtb = wave >> 2;          // base row-tile: waves 0-3 -> {0,2}, 4-7 -> {1,3}
    const int utm = wave & 3;           // unit-tile residue
    const int lofs = lane * 8;          // element offset of this lane's frag

    // ---- GEMM1 B-frags: X^T = [z_cond | c | 0pad], per row-tile ----
    Frag bx[2];
    #pragma unroll
    for (int i = 0; i < 2; ++i) {
        const int n = (rtb + 2 * i) * 16 + l15;
        const float* zr = z + (size_t)(row0 + n) * DIN;
        const float* cr = c + (size_t)(row0 + n) * DC;
        float v[8];
        if (quad == 0) {
            #pragma unroll
            for (int j = 0; j < 8; ++j) {
                const int col = ((j >> p) << (p + 1)) | (cv << p) | (j & lowmask);
                v[j] = zr[col];
            }
        } else if (quad == 1) {
            #pragma unroll
            for (int j = 0; j < 8; ++j) v[j] = cr[j];
        } else if (quad == 2) {
            #pragma unroll
            for (int j = 0; j < 8; ++j) v[j] = cr[8 + j];
        } else {
            #pragma unroll
            for (int j = 0; j < 8; ++j) v[j] = 0.f;
        }
        #pragma unroll
        for (int j = 0; j < 4; ++j) bx[i].u32[j] = pack2h(v[2 * j], v[2 * j + 1]);
    }

    // ---- GEMM1: H0^T = relu(W0F @ X^T + b0), straight into swizzled LDS ----
    #pragma unroll
    for (int j = 0; j < 8; ++j) {
        const int ut = utm + 4 * j;
        Frag a; a.q = *(const uint4*)(W0F + (ut << 9) + lofs);
        const f32x4 bias = *(const f32x4*)(b0 + ut * 16 + quad * 4);
        const int m0 = ut * 16 + quad * 4;
        #pragma unroll
        for (int i = 0; i < 2; ++i) {
            f32x4 acc = __builtin_amdgcn_mfma_f32_16x16x32_f16(a.v, bx[i].v, bias, 0, 0, 0);
            const int n = (rtb + 2 * i) * 16 + l15;
            uint2 w2;
            w2.x = pack2h(fmaxf(acc.x, 0.f), fmaxf(acc.y, 0.f));
            w2.y = pack2h(fmaxf(acc.z, 0.f), fmaxf(acc.w, 0.f));
            const int addr = n * 1024 + (((m0 >> 3) ^ (n & 7)) * 16) + ((m0 & 4) * 2);
            *(uint2*)(smem + addr) = w2;
        }
    }
    __syncthreads();

    // ---- GEMM2: H1 = relu(H0 @ W1 + b1), H1 kept in registers ----
    f32x4 h1[8][2];
    #pragma unroll
    for (int j = 0; j < 8; ++j) {
        const int ut = utm + 4 * j;
        const f32x4 bias = *(const f32x4*)(b1 + ut * 16 + quad * 4);
        h1[j][0] = bias; h1[j][1] = bias;
    }
    #pragma unroll 2
    for (int ks = 0; ks < 16; ++ks) {
        Frag B0, B1;
        {
            const int n0 = rtb * 16 + l15;
            const int n1 = (rtb + 2) * 16 + l15;
            B0.v = *(const h16x8*)(smem + n0 * 1024 + (((ks * 4 + quad) ^ (n0 & 7)) * 16));
            B1.v = *(const h16x8*)(smem + n1 * 1024 + (((ks * 4 + quad) ^ (n1 & 7)) * 16));
        }
        #pragma unroll
        for (int j = 0; j < 8; ++j) {
            const int ut = utm + 4 * j;
            Frag a; a.q = *(const uint4*)(W1F + (((ut << 4) + ks) << 9) + lofs);
            h1[j][0] = __builtin_amdgcn_mfma_f32_16x16x32_f16(a.v, B0.v, h1[j][0], 0, 0, 0);
            h1[j][1] = __builtin_amdgcn_mfma_f32_16x16x32_f16(a.v, B1.v, h1[j][1], 0, 0, 0);
        }
    }
    __syncthreads();

    // ---- GEMM3: P = H1 @ W2 + b2, H1 staged through LDS in 128-unit chunks ----
    f32x4 pacc[2][4];
    #pragma unroll
    for (int i2 = 0; i2 < 2; ++i2) {
        const int m0 = (wave * 2 + i2) * 16 + quad * 4;
        f32x4 bias;
        if (m0 < FOUT) bias = *(const f32x4*)(b2 + m0);
        else { bias.x = 0.f; bias.y = 0.f; bias.z = 0.f; bias.w = 0.f; }
        #pragma unroll
        for (int rt = 0; rt < 4; ++rt) pacc[i2][rt] = bias;
    }
    for (int c2 = 0; c2 < 4; ++c2) {
        // stage H1 units [c2*128, c2*128+128) -> LDS (16 KB, swizzled)
        #pragma unroll
        for (int jj = 0; jj < 2; ++jj) {
            const int j  = 2 * c2 + jj;
            const int ut = utm + 4 * j;                 // in [8*c2, 8*c2+8)
            const int m0l = (ut - c2 * 8) * 16 + quad * 4;  // 0..127
            #pragma unroll
            for (int i = 0; i < 2; ++i) {
                const int n = (rtb + 2 * i) * 16 + l15;
                uint2 w2;
                w2.x = pack2h(fmaxf(h1[j][i].x, 0.f), fmaxf(h1[j][i].y, 0.f));
                w2.y = pack2h(fmaxf(h1[j][i].z, 0.f), fmaxf(h1[j][i].w, 0.f));
                const int addr = n * 256 + ((((m0l >> 3) ^ (n & 7)) & 15) * 16) + ((m0l & 4) * 2);
                *(uint2*)(smem + addr) = w2;
            }
        }
        __syncthreads();
        #pragma unroll
        for (int ks2 = 0; ks2 < 4; ++ks2) {
            Frag B[4];
            #pragma unroll
            for (int rt = 0; rt < 4; ++rt) {
                const int n = rt * 16 + l15;
                const int ch = ((ks2 * 4 + quad) ^ (n & 7)) & 15;
                B[rt].v = *(const h16x8*)(smem + n * 256 + ch * 16);
            }
            #pragma unroll
            for (int i2 = 0; i2 < 2; ++i2) {
                const int ut2 = wave * 2 + i2;
                Frag a; a.q = *(const uint4*)(W2F + ((((ut2 << 2) + c2) << 2 | ks2) << 9) + lofs);
                #pragma unroll
                for (int rt = 0; rt < 4; ++rt)
                    pacc[i2][rt] = __builtin_amdgcn_mfma_f32_16x16x32_f16(a.v, B[rt].v, pacc[i2][rt], 0, 0, 0);
            }
        }
        __syncthreads();
    }

    // ---- dump P (fp32) to LDS for the spline phase: [64 rows][252] ----
    #pragma unroll
    for (int i2 = 0; i2 < 2; ++i2) {
        const int m0 = (wave * 2 + i2) * 16 + quad * 4;
        if (m0 < FOUT) {
            #pragma unroll
            for (int rt = 0; rt < 4; ++rt) {
                const int n = rt * 16 + l15;
                *(f32x4*)(smem + n * 1008 + m0 * 4) = pacc[i2][rt];
            }
        }
    }
    __syncthreads();

    // ---- RQS spline: thread t -> (row r = t>>3, dim d = t&7) ----
    {
        const int r = t >> 3;
        const int d = t & 7;
        const int row = row0 + r;
        const int td = ((d >> p) << (p + 1)) | (tv << p) | (d & lowmask);
        const float* pp = (const float*)(smem + r * 1008) + d * 31;

        float mw = pp[0];
        #pragma unroll
        for (int i = 1; i < BINS; ++i) mw = fmaxf(mw, pp[i]);
        float w[BINS]; float sw = 0.f;
        #pragma unroll
        for (int i = 0; i < BINS; ++i) { w[i] = expf(pp[i] - mw); sw += w[i]; }
        const float rw = (1.0f - 0.001f * BINS) / sw;
        #pragma unroll
        for (int i = 0; i < BINS; ++i) w[i] = 0.001f + rw * w[i];

        float mh = pp[BINS];
        #pragma unroll
        for (int i = 1; i < BINS; ++i) mh = fmaxf(mh, pp[BINS + i]);
        float hh[BINS]; float sh = 0.f;
        #pragma unroll
        for (int i = 0; i < BINS; ++i) { hh[i] = expf(pp[BINS + i] - mh); sh += hh[i]; }
        const float rh = (1.0f - 0.001f * BINS) / sh;
        #pragma unroll
        for (int i = 0; i < BINS; ++i) hh[i] = 0.001f + rh * hh[i];

        float dd[BINS + 1];
        #pragma unroll
        for (int i = 0; i < BINS + 1; ++i) {
            const float u = pp[2 * BINS + i];
            dd[i] = 0.001f + fmaxf(u, 0.f) + log1pf(expf(-fabsf(u)));
        }

        float cw[BINS + 1], ch[BINS + 1];
        cw[0] = 0.f; ch[0] = 0.f;
        #pragma unroll
        for (int i = 0; i < BINS; ++i) { cw[i + 1] = cw[i] + w[i]; ch[i + 1] = ch[i] + hh[i]; }

        const float x = z[(size_t)row * DIN + td];

        int cnt = 0;
        #pragma unroll
        for (int i = 0; i <= BINS; ++i) cnt += (x >= cw[i]) ? 1 : 0;
        int idx = cnt - 1;
        idx = idx < 0 ? 0 : (idx > BINS - 1 ? BINS - 1 : idx);

        float xk = 0.f, wk = 1.f, yk = 0.f, hk = 1.f, dk = 1.f, dk1 = 1.f;
        #pragma unroll
        for (int i = 0; i < BINS; ++i) {
            if (idx == i) { xk = cw[i]; wk = w[i]; yk = ch[i]; hk = hh[i]; dk = dd[i]; dk1 = dd[i + 1]; }
        }

        float th = (x - xk) / wk;
        th = fminf(fmaxf(th, 0.f), 1.f);
        const float s   = hk / wk;
        const float t1  = th * (1.f - th);
        const float den = s + (dk1 + dk - 2.f * s) * t1;
        const float num = s * th * th + dk * t1;
        const float y   = yk + hk * num / den;
        const float om  = 1.f - th;
        float ljv = 2.f * logf(s)
                  + logf(dk1 * th * th + 2.f * s * t1 + dk * om * om)
                  - 2.f * logf(den);

        zout[(size_t)row * DIN + td] = y;

        float v = ljv;
        v += __shfl_down(v, 4, 8);
        v += __shfl_down(v, 2, 8);
        v += __shfl_down(v, 1, 8);
        if ((t & 7) == 0) logdet[row0 + (t >> 3)] += v;
    }
}

extern "C" void kernel_launch(void* const* d_in, const int* in_sizes, int n_in,
                              void* d_out, int out_size, void* d_ws, size_t ws_size,
                              hipStream_t stream) {
    (void)in_sizes; (void)n_in; (void)out_size; (void)ws_size;
    const float* x  = (const float*)d_in[0];
    const float* c  = (const float*)d_in[1];
    const float* W0 = (const float*)d_in[2];
    const float* b0 = (const float*)d_in[3];
    const float* W1 = (const float*)d_in[4];
    const float* b1 = (const float*)d_in[5];
    const float* W2 = (const float*)d_in[6];
    const float* b2 = (const float*)d_in[7];
    float* out = (float*)d_out;

    char* ws = (char*)d_ws;
    float* z = (float*)(ws + Z_OFF);
    _Float16* W0F = (_Float16*)(ws + W0F_OFF);
    _Float16* W1F = (_Float16*)(ws + W1F_OFF);
    _Float16* W2F = (_Float16*)(ws + W2F_OFF);

    hipMemcpyAsync(z, x, (size_t)NROWS * DIN * sizeof(float),
                   hipMemcpyDeviceToDevice, stream);
    hipMemsetAsync(out, 0, (size_t)NROWS * sizeof(float), stream);

    prep_weights<<<12800, 256, 0, stream>>>(W0, W1, W2, W0F, W1F, W2F);

    dim3 grid(NWG), block(512);
    for (int b = 0; b < 8; ++b) {
        const int p = b >> 1, inv = b & 1;
        flow_block_kernel<<<grid, block, 0, stream>>>(
            z, c,
            W0F + (size_t)b * 32 * 512,          b0 + (size_t)b * UNITS,
            W1F + (size_t)b * 32 * 16 * 512,     b1 + (size_t)b * UNITS,
            W2F + (size_t)b * 16 * 4 * 4 * 512,  b2 + (size_t)b * FOUT,
            z, out, p, inv);
    }
}

// Round 5
// 1369.842 us; speedup vs baseline: 10.2383x; 1.5125x over previous
//
#include <hip/hip_runtime.h>
#include <math.h>

#define NROWS 131072
#define DIN   16
#define DC    16
#define UNITS 512
#define BINS  10
#define DT    8
#define FOUT  248
#define M_TILE 64               // rows per workgroup
#define NWG   (NROWS / M_TILE)  // 2048

// d_ws byte offsets
#define Z_OFF    0u
#define W0F_OFF  8388608u   // [8][32 ut][512]          fp16, fragment-major
#define W1F_OFF  8650752u   // [8][32 ut][16 ks][512]   fp16, fragment-major
#define W2F_OFF  12845056u  // [8][16 ut2][4 c2][4 ks2][512] fp16, fragment-major

typedef _Float16 h16x8 __attribute__((ext_vector_type(8)));
typedef float    f32x4 __attribute__((ext_vector_type(4)));

union Frag { h16x8 v; uint4 q; unsigned int u32[4]; _Float16 h[8]; };

static __device__ inline unsigned int pack2h(float lo, float hi) {
    union { _Float16 h[2]; unsigned int u; } x;
    x.h[0] = (_Float16)lo; x.h[1] = (_Float16)hi;
    return x.u;
}

// ---------------- weight convert prologue: fragment-major layouts ----------------
// lane = quad*16 + l15.  A-frag element j of lane -> weight (m, k):
//   m = ut*16 + l15,  k = kbase + quad*8 + j
__global__ __launch_bounds__(256)
void prep_weights(const float* __restrict__ W0, const float* __restrict__ W1,
                  const float* __restrict__ W2, _Float16* __restrict__ W0F,
                  _Float16* __restrict__ W1F, _Float16* __restrict__ W2F)
{
    const int idx = blockIdx.x * 256 + threadIdx.x;
    const int SZ0 = 8 * 32 * 512;           // 131072
    const int SZ1 = 8 * 32 * 16 * 512;      // 2097152
    const int SZ2 = 8 * 16 * 4 * 4 * 512;   // 1048576
    if (idx < SZ0) {
        int b = idx >> 14, r = idx & 16383;
        int ut = r >> 9, le = r & 511;
        int lane = le >> 3, j = le & 7;
        int quad = lane >> 4, l15 = lane & 15;
        int m = ut * 16 + l15, k = quad * 8 + j;
        W0F[idx] = (k < 24) ? (_Float16)W0[b * (24 * 512) + k * 512 + m] : (_Float16)0.f;
    } else if (idx < SZ0 + SZ1) {
        int i = idx - SZ0;
        int b = i >> 18, r = i & 262143;
        int ut = r >> 13, r2 = r & 8191;
        int ks = r2 >> 9, le = r2 & 511;
        int lane = le >> 3, j = le & 7;
        int quad = lane >> 4, l15 = lane & 15;
        int m = ut * 16 + l15, k = ks * 32 + quad * 8 + j;
        W1F[i] = (_Float16)W1[(b << 18) + k * 512 + m];
    } else if (idx < SZ0 + SZ1 + SZ2) {
        int i = idx - SZ0 - SZ1;
        int b = i >> 17, r = i & 131071;
        int ut2 = r >> 13, r2 = r & 8191;
        int c2 = r2 >> 11, r3 = r2 & 2047;
        int ks2 = r3 >> 9, le = r3 & 511;
        int lane = le >> 3, j = le & 7;
        int quad = lane >> 4, l15 = lane & 15;
        int m = ut2 * 16 + l15, k = c2 * 128 + ks2 * 32 + quad * 8 + j;
        W2F[i] = (m < FOUT) ? (_Float16)W2[b * (512 * FOUT) + k * FOUT + m] : (_Float16)0.f;
    }
}

// ---------------- fused coupling block ----------------
// Waves: wave w in 0..7. GEMM1/2: uts {4w..4w+3} x row-tiles {0..3}.
// GEMM3: ut2 {2w, 2w+1} x row-tiles {0..3}.
__global__ __launch_bounds__(512, 4)
void flow_block_kernel(const float* __restrict__ z, const float* __restrict__ c,
                       const _Float16* __restrict__ W0F, const float* __restrict__ b0,
                       const _Float16* __restrict__ W1F, const float* __restrict__ b1,
                       const _Float16* __restrict__ W2F, const float* __restrict__ b2,
                       float* __restrict__ zout, float* __restrict__ logdet,
                       int p, int inv)
{
    __shared__ __align__(16) char smem[65536];

    const int t    = threadIdx.x;
    const int wave = t >> 6;
    const int lane = t & 63;
    const int quad = lane >> 4;
    const int l15  = lane & 15;
    const int row0 = blockIdx.x * M_TILE;
    const int lowmask = (1 << p) - 1;
    const int cv = 1 - inv, tv = inv;
    const int lofs = lane * 8;          // element offset of this lane's frag

    // ---- GEMM1 B-frags: X^T = [z_cond | c | 0pad], one per row-tile ----
    Frag bx[4];
    #pragma unroll
    for (int rt = 0; rt < 4; ++rt) {
        const int n = rt * 16 + l15;
        const float* zr = z + (size_t)(row0 + n) * DIN;
        const float* cr = c + (size_t)(row0 + n) * DC;
        float v[8];
        if (quad == 0) {
            #pragma unroll
            for (int j = 0; j < 8; ++j) {
                const int col = ((j >> p) << (p + 1)) | (cv << p) | (j & lowmask);
                v[j] = zr[col];
            }
        } else if (quad == 1) {
            #pragma unroll
            for (int j = 0; j < 8; ++j) v[j] = cr[j];
        } else if (quad == 2) {
            #pragma unroll
            for (int j = 0; j < 8; ++j) v[j] = cr[8 + j];
        } else {
            #pragma unroll
            for (int j = 0; j < 8; ++j) v[j] = 0.f;
        }
        #pragma unroll
        for (int j = 0; j < 4; ++j) bx[rt].u32[j] = pack2h(v[2 * j], v[2 * j + 1]);
    }

    // ---- GEMM1: H0^T = relu(W0F @ X^T + b0) -> swizzled LDS ----
    #pragma unroll
    for (int j = 0; j < 4; ++j) {
        const int ut = wave * 4 + j;
        Frag a; a.q = *(const uint4*)(W0F + (ut << 9) + lofs);
        const f32x4 bias = *(const f32x4*)(b0 + ut * 16 + quad * 4);
        const int m0 = ut * 16 + quad * 4;
        #pragma unroll
        for (int rt = 0; rt < 4; ++rt) {
            f32x4 acc = __builtin_amdgcn_mfma_f32_16x16x32_f16(a.v, bx[rt].v, bias, 0, 0, 0);
            const int n = rt * 16 + l15;
            uint2 w2;
            w2.x = pack2h(fmaxf(acc.x, 0.f), fmaxf(acc.y, 0.f));
            w2.y = pack2h(fmaxf(acc.z, 0.f), fmaxf(acc.w, 0.f));
            const int addr = n * 1024 + (((m0 >> 3) ^ (n & 7)) * 16) + ((m0 & 4) * 2);
            *(uint2*)(smem + addr) = w2;
        }
    }
    __syncthreads();

    // ---- GEMM2: H1 = relu(H0 @ W1 + b1), kept in registers ----
    f32x4 h1[4][4];   // [j][rt]
    #pragma unroll
    for (int j = 0; j < 4; ++j) {
        const int ut = wave * 4 + j;
        const f32x4 bias = *(const f32x4*)(b1 + ut * 16 + quad * 4);
        #pragma unroll
        for (int rt = 0; rt < 4; ++rt) h1[j][rt] = bias;
    }
    #pragma unroll 2
    for (int ks = 0; ks < 16; ++ks) {
        Frag B[4];
        #pragma unroll
        for (int rt = 0; rt < 4; ++rt) {
            const int n = rt * 16 + l15;
            B[rt].v = *(const h16x8*)(smem + n * 1024 + (((ks * 4 + quad) ^ (n & 7)) * 16));
        }
        #pragma unroll
        for (int j = 0; j < 4; ++j) {
            const int ut = wave * 4 + j;
            Frag a; a.q = *(const uint4*)(W1F + (((ut << 4) + ks) << 9) + lofs);
            #pragma unroll
            for (int rt = 0; rt < 4; ++rt)
                h1[j][rt] = __builtin_amdgcn_mfma_f32_16x16x32_f16(a.v, B[rt].v, h1[j][rt], 0, 0, 0);
        }
    }
    __syncthreads();   // everyone done reading H0

    // ---- stage full H1 (relu, fp16) into the same 64 KB swizzled LDS ----
    #pragma unroll
    for (int j = 0; j < 4; ++j) {
        const int ut = wave * 4 + j;
        const int m0 = ut * 16 + quad * 4;
        #pragma unroll
        for (int rt = 0; rt < 4; ++rt) {
            const int n = rt * 16 + l15;
            uint2 w2;
            w2.x = pack2h(fmaxf(h1[j][rt].x, 0.f), fmaxf(h1[j][rt].y, 0.f));
            w2.y = pack2h(fmaxf(h1[j][rt].z, 0.f), fmaxf(h1[j][rt].w, 0.f));
            const int addr = n * 1024 + (((m0 >> 3) ^ (n & 7)) * 16) + ((m0 & 4) * 2);
            *(uint2*)(smem + addr) = w2;
        }
    }
    __syncthreads();

    // ---- GEMM3: P = H1 @ W2 + b2, barrier-free K-stream ----
    f32x4 pacc[2][4];
    #pragma unroll
    for (int i2 = 0; i2 < 2; ++i2) {
        const int m0 = (wave * 2 + i2) * 16 + quad * 4;
        f32x4 bias;
        if (m0 < FOUT) bias = *(const f32x4*)(b2 + m0);
        else { bias.x = 0.f; bias.y = 0.f; bias.z = 0.f; bias.w = 0.f; }
        #pragma unroll
        for (int rt = 0; rt < 4; ++rt) pacc[i2][rt] = bias;
    }
    #pragma unroll 2
    for (int kk = 0; kk < 16; ++kk) {      // kk = c2*4 + ks2
        const int kc = kk * 4 + quad;      // chunk index 0..63
        Frag B[4];
        #pragma unroll
        for (int rt = 0; rt < 4; ++rt) {
            const int n = rt * 16 + l15;
            B[rt].v = *(const h16x8*)(smem + n * 1024 + ((kc ^ (n & 7)) * 16));
        }
        #pragma unroll
        for (int i2 = 0; i2 < 2; ++i2) {
            const int ut2 = wave * 2 + i2;
            Frag a; a.q = *(const uint4*)(W2F + (((ut2 << 4) + kk) << 9) + lofs);
            #pragma unroll
            for (int rt = 0; rt < 4; ++rt)
                pacc[i2][rt] = __builtin_amdgcn_mfma_f32_16x16x32_f16(a.v, B[rt].v, pacc[i2][rt], 0, 0, 0);
        }
    }
    __syncthreads();   // H1 reads done; reuse LDS for fp32 P

    // ---- dump P (fp32) to LDS for the spline phase: [64 rows][252] ----
    #pragma unroll
    for (int i2 = 0; i2 < 2; ++i2) {
        const int m0 = (wave * 2 + i2) * 16 + quad * 4;
        if (m0 < FOUT) {
            #pragma unroll
            for (int rt = 0; rt < 4; ++rt) {
                const int n = rt * 16 + l15;
                *(f32x4*)(smem + n * 1008 + m0 * 4) = pacc[i2][rt];
            }
        }
    }
    __syncthreads();

    // ---- RQS spline: thread t -> (row r = t>>3, dim d = t&7) ----
    {
        const int r = t >> 3;
        const int d = t & 7;
        const int row = row0 + r;
        const int td = ((d >> p) << (p + 1)) | (tv << p) | (d & lowmask);
        const float* pp = (const float*)(smem + r * 1008) + d * 31;

        float mw = pp[0];
        #pragma unroll
        for (int i = 1; i < BINS; ++i) mw = fmaxf(mw, pp[i]);
        float w[BINS]; float sw = 0.f;
        #pragma unroll
        for (int i = 0; i < BINS; ++i) { w[i] = expf(pp[i] - mw); sw += w[i]; }
        const float rw = (1.0f - 0.001f * BINS) / sw;
        #pragma unroll
        for (int i = 0; i < BINS; ++i) w[i] = 0.001f + rw * w[i];

        float mh = pp[BINS];
        #pragma unroll
        for (int i = 1; i < BINS; ++i) mh = fmaxf(mh, pp[BINS + i]);
        float hh[BINS]; float sh = 0.f;
        #pragma unroll
        for (int i = 0; i < BINS; ++i) { hh[i] = expf(pp[BINS + i] - mh); sh += hh[i]; }
        const float rh = (1.0f - 0.001f * BINS) / sh;
        #pragma unroll
        for (int i = 0; i < BINS; ++i) hh[i] = 0.001f + rh * hh[i];

        float dd[BINS + 1];
        #pragma unroll
        for (int i = 0; i < BINS + 1; ++i) {
            const float u = pp[2 * BINS + i];
            dd[i] = 0.001f + fmaxf(u, 0.f) + log1pf(expf(-fabsf(u)));
        }

        float cw[BINS + 1], ch[BINS + 1];
        cw[0] = 0.f; ch[0] = 0.f;
        #pragma unroll
        for (int i = 0; i < BINS; ++i) { cw[i + 1] = cw[i] + w[i]; ch[i + 1] = ch[i] + hh[i]; }

        const float x = z[(size_t)row * DIN + td];

        int cnt = 0;
        #pragma unroll
        for (int i = 0; i <= BINS; ++i) cnt += (x >= cw[i]) ? 1 : 0;
        int idx = cnt - 1;
        idx = idx < 0 ? 0 : (idx > BINS - 1 ? BINS - 1 : idx);

        float xk = 0.f, wk = 1.f, yk = 0.f, hk = 1.f, dk = 1.f, dk1 = 1.f;
        #pragma unroll
        for (int i = 0; i < BINS; ++i) {
            if (idx == i) { xk = cw[i]; wk = w[i]; yk = ch[i]; hk = hh[i]; dk = dd[i]; dk1 = dd[i + 1]; }
        }

        float th = (x - xk) / wk;
        th = fminf(fmaxf(th, 0.f), 1.f);
        const float s   = hk / wk;
        const float t1  = th * (1.f - th);
        const float den = s + (dk1 + dk - 2.f * s) * t1;
        const float num = s * th * th + dk * t1;
        const float y   = yk + hk * num / den;
        const float om  = 1.f - th;
        float ljv = 2.f * logf(s)
                  + logf(dk1 * th * th + 2.f * s * t1 + dk * om * om)
                  - 2.f * logf(den);

        zout[(size_t)row * DIN + td] = y;

        float v = ljv;
        v += __shfl_down(v, 4, 8);
        v += __shfl_down(v, 2, 8);
        v += __shfl_down(v, 1, 8);
        if ((t & 7) == 0) logdet[row0 + (t >> 3)] += v;
    }
}

extern "C" void kernel_launch(void* const* d_in, const int* in_sizes, int n_in,
                              void* d_out, int out_size, void* d_ws, size_t ws_size,
                              hipStream_t stream) {
    (void)in_sizes; (void)n_in; (void)out_size; (void)ws_size;
    const float* x  = (const float*)d_in[0];
    const float* c  = (const float*)d_in[1];
    const float* W0 = (const float*)d_in[2];
    const float* b0 = (const float*)d_in[3];
    const float* W1 = (const float*)d_in[4];
    const float* b1 = (const float*)d_in[5];
    const float* W2 = (const float*)d_in[6];
    const float* b2 = (const float*)d_in[7];
    float* out = (float*)d_out;

    char* ws = (char*)d_ws;
    float* z = (float*)(ws + Z_OFF);
    _Float16* W0F = (_Float16*)(ws + W0F_OFF);
    _Float16* W1F = (_Float16*)(ws + W1F_OFF);
    _Float16* W2F = (_Float16*)(ws + W2F_OFF);

    hipMemcpyAsync(z, x, (size_t)NROWS * DIN * sizeof(float),
                   hipMemcpyDeviceToDevice, stream);
    hipMemsetAsync(out, 0, (size_t)NROWS * sizeof(float), stream);

    prep_weights<<<12800, 256, 0, stream>>>(W0, W1, W2, W0F, W1F, W2F);

    dim3 grid(NWG), block(512);
    for (int b = 0; b < 8; ++b) {
        const int p = b >> 1, inv = b & 1;
        flow_block_kernel<<<grid, block, 0, stream>>>(
            z, c,
            W0F + (size_t)b * 32 * 512,          b0 + (size_t)b * UNITS,
            W1F + (size_t)b * 32 * 16 * 512,     b1 + (size_t)b * UNITS,
            W2F + (size_t)b * 16 * 4 * 4 * 512,  b2 + (size_t)b * FOUT,
            z, out, p, inv);
    }
}